// Round 9
// baseline (386.440 us; speedup 1.0000x reference)
//
#include <hip/hip_runtime.h>
#include <hip/hip_bf16.h>
#include <math.h>

#define N_NODES 50000
#define E_EDGES 1600000
#define NBKT 196          // row buckets of 256 rows
#define PBLK 400          // blocks in hist/scatter phases
#define CHUNK 4000        // edges per block (PBLK*CHUNK == E_EDGES)

typedef __attribute__((ext_vector_type(8))) short s8v;    // 8 bf16 frag
typedef __attribute__((ext_vector_type(4))) float f32x4;  // mfma acc

// ---------------- workspace layout (float units) ----------------
#define O_BLKH  0          // 196*400 u32, local-scanned in place
#define O_BBASE 78592      // 197 u32 bucket bases
#define O_BSUM  78848      // 196 u32 bucket totals
#define O_CNT   79104      // 50000 i32
#define O_DINV  129152     // 50000 f32
#define O_RPTR  179200     // 50000 i32
#define O_SREC  229248     // 1.6M u64 records = 3.2M floats
#define O_SREC2 3429248    // 1.6M u64 sorted records
#define O_EDGE  O_SREC     // alias: final u32 edges (srec dead after k_csr)
#define O_XHQ   O_SREC2    // alias: quarter-major [4][N][16u32] (srec2 dead)
#define O_T1Q   6629248
#define O_T2Q   9829248
#define O_BP    13029248   // 98304 bf16
// end: 13078400 floats ~= 52.3 MB

__device__ __forceinline__ uint pk_bf16(float x, float y) {
  __hip_bfloat16 bx = __float2bfloat16(x), by = __float2bfloat16(y);
  ushort ux = *reinterpret_cast<ushort*>(&bx);
  ushort uy = *reinterpret_cast<ushort*>(&by);
  return ((uint)uy << 16) | (uint)ux;
}

// ---- phase 1: per-block bucket histogram (no global atomics) ----
__global__ __launch_bounds__(256) void k_hist(const int* __restrict__ ei,
                                              uint* __restrict__ blkh) {
  __shared__ uint h[NBKT];
  int blk = blockIdx.x, tid = threadIdx.x;
  for (int i = tid; i < NBKT; i += 256) h[i] = 0;
  __syncthreads();
  int e0 = blk * CHUNK;
  for (int i = tid; i < CHUNK; i += 256) {
    int e = e0 + i;
    int r = ei[e], c = ei[E_EDGES + e];
    if (r != c) atomicAdd(&h[r >> 8], 1u);
  }
  __syncthreads();
  for (int i = tid; i < NBKT; i += 256) blkh[i * PBLK + blk] = h[i];  // [bucket][block]
}

// ---- phase 2a: per-bucket exclusive scan of its 400 block counts + total ----
__global__ __launch_bounds__(256) void k_bsum_scan(uint* __restrict__ blkh,
                                                   uint* __restrict__ bsum) {
  __shared__ uint sh[512];
  int b = blockIdx.x, t = threadIdx.x;
  uint v0 = (t < PBLK) ? blkh[b * PBLK + t] : 0u;
  uint v1 = (t + 256 < PBLK) ? blkh[b * PBLK + t + 256] : 0u;
  sh[t] = v0; sh[t + 256] = v1;
  __syncthreads();
  for (int off = 1; off < 512; off <<= 1) {
    uint x0 = sh[t], x1 = sh[t + 256];
    uint a0 = (t >= off) ? sh[t - off] : 0u;
    uint a1 = (t + 256 >= off) ? sh[t + 256 - off] : 0u;
    __syncthreads();
    sh[t] = x0 + a0; sh[t + 256] = x1 + a1;
    __syncthreads();
  }
  if (t < PBLK) blkh[b * PBLK + t] = sh[t] - v0;          // local exclusive
  if (t + 256 < PBLK) blkh[b * PBLK + t + 256] = sh[t + 256] - v1;
  if (t == 0) bsum[b] = sh[511];
}

// ---- phase 2b: scan 196 bucket totals -> bbase[0..196] ----
__global__ __launch_bounds__(256) void k_bscan(const uint* __restrict__ bsum,
                                               uint* __restrict__ bbase) {
  __shared__ uint sh[256];
  int t = threadIdx.x;
  uint v = (t < NBKT) ? bsum[t] : 0u;
  sh[t] = v;
  __syncthreads();
  for (int off = 1; off < 256; off <<= 1) {
    uint a = (t >= off) ? sh[t - off] : 0u;
    __syncthreads();
    sh[t] += a;
    __syncthreads();
  }
  if (t < NBKT) bbase[t] = sh[t] - v;
  if (t == 255) bbase[NBKT] = sh[255];
}

// ---- phase 3: scatter edges to bucket-contiguous u64 records via LDS cursors ----
__global__ __launch_bounds__(256) void k_scatter_b(const int* __restrict__ ei,
                                                   const float* __restrict__ ew,
                                                   const uint* __restrict__ off,
                                                   const uint* __restrict__ bbase,
                                                   unsigned long long* __restrict__ srec) {
  __shared__ uint cur[NBKT];
  int blk = blockIdx.x, tid = threadIdx.x;
  for (int i = tid; i < NBKT; i += 256) cur[i] = off[i * PBLK + blk] + bbase[i];
  __syncthreads();
  int e0 = blk * CHUNK;
  for (int i = tid; i < CHUNK; i += 256) {
    int e = e0 + i;
    int r = ei[e], c = ei[E_EDGES + e];
    if (r != c) {
      uint pos = atomicAdd(&cur[r >> 8], 1u);
      srec[pos] = ((unsigned long long)(r & 255) << 48) |
                  ((unsigned long long)(uint)c << 32) |
                  (unsigned long long)__float_as_uint(ew[e]);
    }
  }
}

// ---- phase 4: per-bucket CSR build + degree/dinv (LDS atomics only) ----
__global__ __launch_bounds__(256) void k_csr(const unsigned long long* __restrict__ srec,
                                             const uint* __restrict__ bbase,
                                             unsigned long long* __restrict__ srec2,
                                             int* __restrict__ cnt, float* __restrict__ dinv,
                                             int* __restrict__ rptr) {
  __shared__ uint hc[256], hs[256], cur[256], wsum[4];
  int b = blockIdx.x, t = threadIdx.x;
  uint start = bbase[b], endv = bbase[b + 1];
  hc[t] = 0; hs[t] = 0;
  __syncthreads();
  for (uint i = start + t; i < endv; i += 256) {
    unsigned long long rec = srec[i];
    int rl = (int)(rec >> 48);
    float w = __uint_as_float((uint)rec);
    atomicAdd(&hc[rl], 1u);
    atomicAdd(&hs[rl], (uint)(w * 1048576.0f + 0.5f));  // fixed 2^20
  }
  __syncthreads();
  int lane = t & 63, wid = t >> 6;
  uint myc = hc[t];
  uint x = myc;
#pragma unroll
  for (int off = 1; off < 64; off <<= 1) {
    uint y = __shfl_up(x, off);
    if (lane >= off) x += y;
  }
  if (lane == 63) wsum[wid] = x;
  __syncthreads();
  uint woff = 0;
#pragma unroll
  for (int j = 0; j < 4; ++j) if (j < wid) woff += wsum[j];
  uint excl = woff + x - myc;
  int row = b * 256 + t;
  if (row < N_NODES) {
    float d = (float)hs[t] * (1.0f / 1048576.0f);
    dinv[row] = d > 0.f ? rsqrtf(d) : 0.f;
    cnt[row] = (int)myc;
    rptr[row] = (int)(start + excl);
  }
  cur[t] = start + excl;
  __syncthreads();
  for (uint i = start + t; i < endv; i += 256) {
    unsigned long long rec = srec[i];
    int rl = (int)(rec >> 48);
    uint pos = atomicAdd(&cur[rl], 1u);
    srec2[pos] = rec;
  }
}

// ---- phase 5: fold dinv into weights, emit final u32 edge records ----
__global__ __launch_bounds__(256) void k_finalize(const unsigned long long* __restrict__ srec2,
                                                  const uint* __restrict__ bbase,
                                                  const float* __restrict__ dinv,
                                                  uint* __restrict__ edges) {
  int b = blockIdx.x, t = threadIdx.x;
  uint start = bbase[b], endv = bbase[b + 1];
  for (uint i = start + t; i < endv; i += 256) {
    unsigned long long rec = srec2[i];
    int rl = (int)(rec >> 48);
    int c = (int)((rec >> 32) & 0xffff);
    float w = __uint_as_float((uint)rec);
    int r = b * 256 + rl;
    float wn = -w * dinv[r] * dinv[c];
    __hip_bfloat16 bw = __float2bfloat16(wn);
    edges[i] = ((uint)c << 16) | (uint)*reinterpret_cast<ushort*>(&bw);
  }
}

// XHq quarter-major: XHq[(j>>4)][n][j&15], u32 j of 64 covers bf16 ch {2j,2j+1}
__global__ void k_xhb(const float* __restrict__ X, const float* __restrict__ Hm,
                      uint* __restrict__ XHq) {
  int t = blockIdx.x * blockDim.x + threadIdx.x;
  if (t >= N_NODES * 64) return;
  int n = t >> 6, j = t & 63;
  float2 v = (j < 32) ? *(const float2*)(X + (long)n * 64 + j * 2)
                      : *(const float2*)(Hm + (long)n * 64 + (j - 32) * 2);
  XHq[((long)(j >> 4) * N_NODES + n) * 16 + (j & 15)] = pk_bf16(v.x, v.y);
}

// quarter-channel SpMM: out[q] = alpha*(L@src[q]) + beta*other[q].
// One wave per row; 16 lanes = 16 u32 channels, 4 edge-slots in flight.
// Quarter from bid&7 so each XCD pair gathers only its 3.2 MB slice (L2-fit).
__global__ __launch_bounds__(256) void k_spmm2q(
    const uint* __restrict__ src, const uint* __restrict__ other,
    float alpha, float beta,
    const int* __restrict__ rptr, const int* __restrict__ cnt,
    const uint* __restrict__ edges, uint* __restrict__ out) {
  int bid = blockIdx.x;
  int q = (bid & 7) >> 1;
  int rg = ((bid >> 3) << 1) + (bid & 1);   // 0..12499, bijective per quarter
  int wid = threadIdx.x >> 6, lane = threadIdx.x & 63;
  int row = rg * 4 + wid;
  int ch = lane & 15, es = lane >> 4;
  const uint* sq = src + (long)q * (N_NODES * 16);
  int start = rptr[row], n = cnt[row];
  float ax = 0.f, ay = 0.f;
  for (int j = es; j < n; j += 4) {
    uint rec = edges[start + j];
    int cc = (int)(rec >> 16);
    float ww = __uint_as_float(rec << 16);
    uint z = sq[cc * 16 + ch];
    ax = fmaf(ww, __uint_as_float(z << 16), ax);
    ay = fmaf(ww, __uint_as_float(z & 0xffff0000u), ay);
  }
  ax += __shfl_xor(ax, 16); ay += __shfl_xor(ay, 16);
  ax += __shfl_xor(ax, 32); ay += __shfl_xor(ay, 32);
  if (es == 0) {
    long o = (long)q * (N_NODES * 16) + (long)row * 16 + ch;
    float ox = alpha * ax, oy = alpha * ay;
    if (beta != 0.f) {
      uint ov = other[o];
      ox += beta * __uint_as_float(ov << 16);
      oy += beta * __uint_as_float(ov & 0xffff0000u);
    }
    out[o] = pk_bf16(ox, oy);
  }
}

// B-frag pack: Bp[((t*16+c)*64+lane)*8+j] = bf16(W[k][col]), k=t*32+(lane>>4)*8+j,
// col = c*16+(lane&15); col = g*64+oc; k-slice s=k/64: even->Wx[g], odd->Wh[g], ord=s>>1
__global__ void k_pack(const float* __restrict__ Wxi, const float* __restrict__ Wxf,
                       const float* __restrict__ Wxc, const float* __restrict__ Wxo,
                       const float* __restrict__ Whi, const float* __restrict__ Whf,
                       const float* __restrict__ Whc, const float* __restrict__ Who,
                       ushort* __restrict__ Bp) {
  int idx = blockIdx.x * blockDim.x + threadIdx.x;
  if (idx >= 12 * 16 * 64 * 8) return;
  int j = idx & 7;
  int lane = (idx >> 3) & 63;
  int c = (idx >> 9) & 15;
  int t = idx >> 13;
  int k = t * 32 + (lane >> 4) * 8 + j;
  int col = c * 16 + (lane & 15);
  int g = col >> 6, oc = col & 63;
  int s = k >> 6, kk = k & 63, ord = s >> 1;
  const float* Wx[4] = {Wxi, Wxf, Wxc, Wxo};
  const float* Wh[4] = {Whi, Whf, Whc, Who};
  const float* W = (s & 1) ? Wh[g] : Wx[g];
  float v = W[(ord * 64 + kk) * 64 + oc];
  __hip_bfloat16 b = __float2bfloat16(v);
  Bp[idx] = *reinterpret_cast<ushort*>(&b);
}

__device__ __forceinline__ float frcp(float x) { return __builtin_amdgcn_rcpf(x); }

// MFMA GEMM + fused LSTM epilogue. A (quarter-major) prefetched to regs;
// B staged to LDS dbuf. Whole B-tile hoisted to regs BEFORE issuing next
// stage so no vmem-alias wait lands in front of the ds_reads.
__global__ __launch_bounds__(256) void k_mfma_lstm(
    const uint* __restrict__ XHq, const uint* __restrict__ T1q,
    const uint* __restrict__ T2q, const float* __restrict__ C,
    const ushort* __restrict__ Bp,
    const float* __restrict__ bxi, const float* __restrict__ bxf,
    const float* __restrict__ bxc, const float* __restrict__ bxo,
    const float* __restrict__ bhi, const float* __restrict__ bhf,
    const float* __restrict__ bhc, const float* __restrict__ bho,
    const float* __restrict__ wci, const float* __restrict__ wcf, const float* __restrict__ wco,
    const float* __restrict__ bi, const float* __restrict__ bf_,
    const float* __restrict__ bc_, const float* __restrict__ bo,
    float* __restrict__ Hout, float* __restrict__ Cout) {
  __shared__ ushort bsh[2][8192];  // 2 x 16 KB B tiles
  int lane = threadIdx.x & 63, wid = threadIdx.x >> 6;
  int row0 = blockIdx.x * 64 + wid * 16;
  int ar = row0 + (lane & 15);
  if (ar > N_NODES - 1) ar = N_NODES - 1;  // clamp: dup rows, outputs masked later

#define STAGE(buf, t)                                                          \
  {                                                                            \
    _Pragma("unroll") for (int qq = 0; qq < 4; ++qq) {                         \
      int seg = wid * 4 + qq;                                                  \
      __builtin_amdgcn_global_load_lds(                                        \
          (const __attribute__((address_space(1))) uint*)(Bp + (t)*8192 +     \
                                                          seg * 512 + lane * 8),\
          (__attribute__((address_space(3))) uint*)&bsh[buf][seg * 512],       \
          16, 0, 0);                                                           \
    }                                                                          \
  }

  STAGE(0, 0)

  const ushort* XHs = (const ushort*)XHq;
  const ushort* T1s = (const ushort*)T1q;
  const ushort* T2s = (const ushort*)T2q;
  s8v a[12];
#pragma unroll
  for (int q = 0; q < 4; ++q) {
    long off = ((long)q * N_NODES + ar) * 32 + (lane >> 4) * 8;
    a[q]     = *(const s8v*)(XHs + off);
    a[4 + q] = *(const s8v*)(T1s + off);
    a[8 + q] = *(const s8v*)(T2s + off);
  }

  f32x4 acc[16];
#pragma unroll
  for (int c = 0; c < 16; ++c) acc[c] = {0.f, 0.f, 0.f, 0.f};

#pragma unroll
  for (int t = 0; t < 12; ++t) {
    int buf = t & 1;
    __syncthreads();             // drains stage(t); nothing else outstanding
    s8v bfr[16];
#pragma unroll
    for (int c = 0; c < 16; ++c)
      bfr[c] = *(const s8v*)(&bsh[buf][c * 512 + lane * 8]);
    if (t < 11) STAGE(buf ^ 1, t + 1)   // DMA overlaps the 16 MFMAs below
#pragma unroll
    for (int c = 0; c < 16; ++c)
      acc[c] = __builtin_amdgcn_mfma_f32_16x16x32_bf16(a[t], bfr[c], acc[c], 0, 0, 0);
  }
#undef STAGE

  int rbase = row0 + ((lane >> 4) << 2);
  int ocl = lane & 15;
#pragma unroll
  for (int j = 0; j < 4; ++j) {
    int oc = j * 16 + ocl;
    float bI = bxi[oc] + bhi[oc] + bi[oc];
    float bF = bxf[oc] + bhf[oc] + bf_[oc];
    float bT = bxc[oc] + bhc[oc] + bc_[oc];
    float bO = bxo[oc] + bho[oc] + bo[oc];
    float wcI = wci[oc], wcF = wcf[oc], wcO = wco[oc];
#pragma unroll
    for (int r = 0; r < 4; ++r) {
      int row = rbase + r;
      if (row < N_NODES) {
        float cv = C[(long)row * 64 + oc];
        float I = frcp(1.f + __expf(-(acc[j][r] + bI + wcI * cv)));
        float F = frcp(1.f + __expf(-(acc[4 + j][r] + bF + wcF * cv)));
        float e2 = __expf(2.f * (acc[8 + j][r] + bT));
        float T = 1.f - 2.f * frcp(e2 + 1.f);
        float cn = F * cv + I * T;
        float O = frcp(1.f + __expf(-(acc[12 + j][r] + bO + wcO * cn)));
        float e2c = __expf(2.f * cn);
        float tc = 1.f - 2.f * frcp(e2c + 1.f);
        Hout[(long)row * 64 + oc] = O * tc;
        Cout[(long)row * 64 + oc] = cn;
      }
    }
  }
}

extern "C" void kernel_launch(void* const* d_in, const int* in_sizes, int n_in,
                              void* d_out, int out_size, void* d_ws, size_t ws_size,
                              hipStream_t stream) {
  (void)in_sizes; (void)n_in; (void)out_size; (void)ws_size;
  const float* X   = (const float*)d_in[0];
  const int*   ei  = (const int*)d_in[1];
  const float* ew  = (const float*)d_in[2];
  const float* H   = (const float*)d_in[3];
  const float* C   = (const float*)d_in[4];
  const float* Wxi = (const float*)d_in[5];
  const float* bxi = (const float*)d_in[6];
  const float* Wxf = (const float*)d_in[7];
  const float* bxf = (const float*)d_in[8];
  const float* Wxc = (const float*)d_in[9];
  const float* bxc = (const float*)d_in[10];
  const float* Wxo = (const float*)d_in[11];
  const float* bxo = (const float*)d_in[12];
  const float* Whi = (const float*)d_in[13];
  const float* bhi = (const float*)d_in[14];
  const float* Whf = (const float*)d_in[15];
  const float* bhf = (const float*)d_in[16];
  const float* Whc = (const float*)d_in[17];
  const float* bhc = (const float*)d_in[18];
  const float* Who = (const float*)d_in[19];
  const float* bho = (const float*)d_in[20];
  const float* wci = (const float*)d_in[21];
  const float* wcf = (const float*)d_in[22];
  const float* wco = (const float*)d_in[23];
  const float* bi  = (const float*)d_in[24];
  const float* bf_ = (const float*)d_in[25];
  const float* bc_ = (const float*)d_in[26];
  const float* bo  = (const float*)d_in[27];

  float* ws = (float*)d_ws;
  uint*   blkh  = (uint*)(ws + O_BLKH);
  uint*   bbase = (uint*)(ws + O_BBASE);
  uint*   bsum  = (uint*)(ws + O_BSUM);
  int*    cnt   = (int*)(ws + O_CNT);
  float*  dinv  = ws + O_DINV;
  int*    rptr  = (int*)(ws + O_RPTR);
  unsigned long long* srec  = (unsigned long long*)(ws + O_SREC);
  unsigned long long* srec2 = (unsigned long long*)(ws + O_SREC2);
  uint*   edges = (uint*)(ws + O_EDGE);
  uint*   XHq   = (uint*)(ws + O_XHQ);
  uint*   T1q   = (uint*)(ws + O_T1Q);
  uint*   T2q   = (uint*)(ws + O_T2Q);
  ushort* Bp    = (ushort*)(ws + O_BP);

  float* Hout = (float*)d_out;
  float* Cout = Hout + N_NODES * 64;

  k_hist<<<PBLK, 256, 0, stream>>>(ei, blkh);
  k_bsum_scan<<<NBKT, 256, 0, stream>>>(blkh, bsum);
  k_bscan<<<1, 256, 0, stream>>>(bsum, bbase);
  k_scatter_b<<<PBLK, 256, 0, stream>>>(ei, ew, blkh, bbase, srec);
  k_csr<<<NBKT, 256, 0, stream>>>(srec, bbase, srec2, cnt, dinv, rptr);
  k_finalize<<<NBKT, 256, 0, stream>>>(srec2, bbase, dinv, edges);
  k_xhb<<<(N_NODES * 64 + 255) / 256, 256, 0, stream>>>(X, H, XHq);
  k_pack<<<(12 * 16 * 64 * 8 + 255) / 256, 256, 0, stream>>>(Wxi, Wxf, Wxc, Wxo,
                                                             Whi, Whf, Whc, Who, Bp);
  // T1 = L @ XH ; T2 = 2 L @ T1 - XH   (quarter-major, 50000 blocks each)
  k_spmm2q<<<N_NODES, 256, 0, stream>>>(XHq, XHq, 1.f, 0.f, rptr, cnt, edges, T1q);
  k_spmm2q<<<N_NODES, 256, 0, stream>>>(T1q, XHq, 2.f, -1.f, rptr, cnt, edges, T2q);
  k_mfma_lstm<<<(N_NODES + 63) / 64, 256, 0, stream>>>(
      XHq, T1q, T2q, C, Bp,
      bxi, bxf, bxc, bxo, bhi, bhf, bhc, bho,
      wci, wcf, wco, bi, bf_, bc_, bo, Hout, Cout);
}

// Round 10
// 320.747 us; speedup vs baseline: 1.2048x; 1.2048x over previous
//
#include <hip/hip_runtime.h>
#include <hip/hip_bf16.h>
#include <math.h>

#define N_NODES 50000
#define E_EDGES 1600000
#define NBKT 196          // row buckets of 256 rows
#define PBLK 400          // blocks in hist/scatter phases
#define CHUNK 4000        // edges per block (PBLK*CHUNK == E_EDGES)

typedef __attribute__((ext_vector_type(8))) short s8v;    // 8 bf16 frag
typedef __attribute__((ext_vector_type(4))) float f32x4;  // mfma acc

// ---------------- workspace layout (float units) ----------------
#define O_BLKH  0          // 196*400 u32, local-scanned in place
#define O_BBASE 78592      // 197 u32 bucket bases
#define O_BSUM  78848      // 196 u32 bucket totals
#define O_CNT   79104      // 50000 i32
#define O_DINV  129152     // 50000 f32
#define O_RPTR  179200     // 50000 i32
#define O_SREC  229248     // 1.6M u64 records = 3.2M floats
#define O_SREC2 3429248    // 1.6M u64 sorted records
#define O_EDGE  O_SREC     // alias: final u32 edges (srec dead after k_csr)
#define O_XHQ   O_SREC2    // alias: quarter-major [4][N][16u32] (srec2 dead)
#define O_T1Q   6629248
#define O_T2Q   9829248
#define O_BP    13029248   // 98304 bf16
// end: 13078400 floats ~= 52.3 MB

__device__ __forceinline__ uint pk_bf16(float x, float y) {
  __hip_bfloat16 bx = __float2bfloat16(x), by = __float2bfloat16(y);
  ushort ux = *reinterpret_cast<ushort*>(&bx);
  ushort uy = *reinterpret_cast<ushort*>(&by);
  return ((uint)uy << 16) | (uint)ux;
}

// ---- phase 1: per-block bucket histogram (no global atomics) ----
__global__ __launch_bounds__(256) void k_hist(const int* __restrict__ ei,
                                              uint* __restrict__ blkh) {
  __shared__ uint h[NBKT];
  int blk = blockIdx.x, tid = threadIdx.x;
  for (int i = tid; i < NBKT; i += 256) h[i] = 0;
  __syncthreads();
  int e0 = blk * CHUNK;
  for (int i = tid; i < CHUNK; i += 256) {
    int e = e0 + i;
    int r = ei[e], c = ei[E_EDGES + e];
    if (r != c) atomicAdd(&h[r >> 8], 1u);
  }
  __syncthreads();
  for (int i = tid; i < NBKT; i += 256) blkh[i * PBLK + blk] = h[i];  // [bucket][block]
}

// ---- phase 2a: per-bucket exclusive scan of its 400 block counts + total ----
__global__ __launch_bounds__(256) void k_bsum_scan(uint* __restrict__ blkh,
                                                   uint* __restrict__ bsum) {
  __shared__ uint sh[512];
  int b = blockIdx.x, t = threadIdx.x;
  uint v0 = (t < PBLK) ? blkh[b * PBLK + t] : 0u;
  uint v1 = (t + 256 < PBLK) ? blkh[b * PBLK + t + 256] : 0u;
  sh[t] = v0; sh[t + 256] = v1;
  __syncthreads();
  for (int off = 1; off < 512; off <<= 1) {
    uint x0 = sh[t], x1 = sh[t + 256];
    uint a0 = (t >= off) ? sh[t - off] : 0u;
    uint a1 = (t + 256 >= off) ? sh[t + 256 - off] : 0u;
    __syncthreads();
    sh[t] = x0 + a0; sh[t + 256] = x1 + a1;
    __syncthreads();
  }
  if (t < PBLK) blkh[b * PBLK + t] = sh[t] - v0;          // local exclusive
  if (t + 256 < PBLK) blkh[b * PBLK + t + 256] = sh[t + 256] - v1;
  if (t == 0) bsum[b] = sh[511];
}

// ---- phase 2b: scan 196 bucket totals -> bbase[0..196] ----
__global__ __launch_bounds__(256) void k_bscan(const uint* __restrict__ bsum,
                                               uint* __restrict__ bbase) {
  __shared__ uint sh[256];
  int t = threadIdx.x;
  uint v = (t < NBKT) ? bsum[t] : 0u;
  sh[t] = v;
  __syncthreads();
  for (int off = 1; off < 256; off <<= 1) {
    uint a = (t >= off) ? sh[t - off] : 0u;
    __syncthreads();
    sh[t] += a;
    __syncthreads();
  }
  if (t < NBKT) bbase[t] = sh[t] - v;
  if (t == 255) bbase[NBKT] = sh[255];
}

// ---- phase 3: scatter edges to bucket-contiguous u64 records via LDS cursors ----
__global__ __launch_bounds__(256) void k_scatter_b(const int* __restrict__ ei,
                                                   const float* __restrict__ ew,
                                                   const uint* __restrict__ off,
                                                   const uint* __restrict__ bbase,
                                                   unsigned long long* __restrict__ srec) {
  __shared__ uint cur[NBKT];
  int blk = blockIdx.x, tid = threadIdx.x;
  for (int i = tid; i < NBKT; i += 256) cur[i] = off[i * PBLK + blk] + bbase[i];
  __syncthreads();
  int e0 = blk * CHUNK;
  for (int i = tid; i < CHUNK; i += 256) {
    int e = e0 + i;
    int r = ei[e], c = ei[E_EDGES + e];
    if (r != c) {
      uint pos = atomicAdd(&cur[r >> 8], 1u);
      srec[pos] = ((unsigned long long)(r & 255) << 48) |
                  ((unsigned long long)(uint)c << 32) |
                  (unsigned long long)__float_as_uint(ew[e]);
    }
  }
}

// ---- phase 4: per-bucket CSR build + degree/dinv (LDS atomics only) ----
__global__ __launch_bounds__(256) void k_csr(const unsigned long long* __restrict__ srec,
                                             const uint* __restrict__ bbase,
                                             unsigned long long* __restrict__ srec2,
                                             int* __restrict__ cnt, float* __restrict__ dinv,
                                             int* __restrict__ rptr) {
  __shared__ uint hc[256], hs[256], cur[256], wsum[4];
  int b = blockIdx.x, t = threadIdx.x;
  uint start = bbase[b], endv = bbase[b + 1];
  hc[t] = 0; hs[t] = 0;
  __syncthreads();
  for (uint i = start + t; i < endv; i += 256) {
    unsigned long long rec = srec[i];
    int rl = (int)(rec >> 48);
    float w = __uint_as_float((uint)rec);
    atomicAdd(&hc[rl], 1u);
    atomicAdd(&hs[rl], (uint)(w * 1048576.0f + 0.5f));  // fixed 2^20
  }
  __syncthreads();
  int lane = t & 63, wid = t >> 6;
  uint myc = hc[t];
  uint x = myc;
#pragma unroll
  for (int off = 1; off < 64; off <<= 1) {
    uint y = __shfl_up(x, off);
    if (lane >= off) x += y;
  }
  if (lane == 63) wsum[wid] = x;
  __syncthreads();
  uint woff = 0;
#pragma unroll
  for (int j = 0; j < 4; ++j) if (j < wid) woff += wsum[j];
  uint excl = woff + x - myc;
  int row = b * 256 + t;
  if (row < N_NODES) {
    float d = (float)hs[t] * (1.0f / 1048576.0f);
    dinv[row] = d > 0.f ? rsqrtf(d) : 0.f;
    cnt[row] = (int)myc;
    rptr[row] = (int)(start + excl);
  }
  cur[t] = start + excl;
  __syncthreads();
  for (uint i = start + t; i < endv; i += 256) {
    unsigned long long rec = srec[i];
    int rl = (int)(rec >> 48);
    uint pos = atomicAdd(&cur[rl], 1u);
    srec2[pos] = rec;
  }
}

// ---- phase 5: fold dinv into weights, emit final u32 edge records ----
__global__ __launch_bounds__(256) void k_finalize(const unsigned long long* __restrict__ srec2,
                                                  const uint* __restrict__ bbase,
                                                  const float* __restrict__ dinv,
                                                  uint* __restrict__ edges) {
  int b = blockIdx.x, t = threadIdx.x;
  uint start = bbase[b], endv = bbase[b + 1];
  for (uint i = start + t; i < endv; i += 256) {
    unsigned long long rec = srec2[i];
    int rl = (int)(rec >> 48);
    int c = (int)((rec >> 32) & 0xffff);
    float w = __uint_as_float((uint)rec);
    int r = b * 256 + rl;
    float wn = -w * dinv[r] * dinv[c];
    __hip_bfloat16 bw = __float2bfloat16(wn);
    edges[i] = ((uint)c << 16) | (uint)*reinterpret_cast<ushort*>(&bw);
  }
}

// XHq quarter-major: XHq[(j>>4)][n][j&15], u32 j of 64 covers bf16 ch {2j,2j+1}
__global__ void k_xhb(const float* __restrict__ X, const float* __restrict__ Hm,
                      uint* __restrict__ XHq) {
  int t = blockIdx.x * blockDim.x + threadIdx.x;
  if (t >= N_NODES * 64) return;
  int n = t >> 6, j = t & 63;
  float2 v = (j < 32) ? *(const float2*)(X + (long)n * 64 + j * 2)
                      : *(const float2*)(Hm + (long)n * 64 + (j - 32) * 2);
  XHq[((long)(j >> 4) * N_NODES + n) * 16 + (j & 15)] = pk_bf16(v.x, v.y);
}

// quarter-channel SpMM, batched records + shfl broadcast + unrolled slots.
// One wave per (row, quarter); 16 lanes = channels, 4 edge slots (es).
// Quarter from bid&7 so each XCD pair touches only its 3.2 MB slice (L2-fit).
__global__ __launch_bounds__(256) void k_spmm2q(
    const uint* __restrict__ src, const uint* __restrict__ other,
    float alpha, float beta,
    const int* __restrict__ rptr, const int* __restrict__ cnt,
    const uint* __restrict__ edges, uint* __restrict__ out) {
  int bid = blockIdx.x;
  int q = (bid & 7) >> 1;
  int rg = ((bid >> 3) << 1) + (bid & 1);   // 0..12499, bijective per quarter
  int wid = threadIdx.x >> 6, lane = threadIdx.x & 63;
  int row = rg * 4 + wid;
  int ch = lane & 15, es = lane >> 4;
  const uint* sq = src + (long)q * (N_NODES * 16);
  int start = rptr[row], n = cnt[row];
  float ax = 0.f, ay = 0.f;
  for (int base = 0; base < n; base += 64) {
    int m = n - base; if (m > 64) m = 64;
    // coalesced 256B record load, zero-padded (rec=0 -> w=+0, cc=0: harmless)
    uint rec = (lane < m) ? edges[start + base + lane] : 0u;
#pragma unroll
    for (int i = 0; i < 16; ++i) {
      if (i * 4 >= m) break;                 // wave-uniform early exit
      uint r = __shfl(rec, i * 4 + es);
      int cc = (int)(r >> 16);
      float ww = __uint_as_float(r << 16);
      uint z = sq[cc * 16 + ch];
      ax = fmaf(ww, __uint_as_float(z << 16), ax);
      ay = fmaf(ww, __uint_as_float(z & 0xffff0000u), ay);
    }
  }
  ax += __shfl_xor(ax, 16); ay += __shfl_xor(ay, 16);
  ax += __shfl_xor(ax, 32); ay += __shfl_xor(ay, 32);
  if (es == 0) {
    long o = (long)q * (N_NODES * 16) + (long)row * 16 + ch;
    float ox = alpha * ax, oy = alpha * ay;
    if (beta != 0.f) {
      uint ov = other[o];
      ox += beta * __uint_as_float(ov << 16);
      oy += beta * __uint_as_float(ov & 0xffff0000u);
    }
    out[o] = pk_bf16(ox, oy);
  }
}

// B-frag pack: Bp[((t*16+c)*64+lane)*8+j] = bf16(W[k][col]), k=t*32+(lane>>4)*8+j,
// col = c*16+(lane&15); col = g*64+oc; k-slice s=k/64: even->Wx[g], odd->Wh[g], ord=s>>1
__global__ void k_pack(const float* __restrict__ Wxi, const float* __restrict__ Wxf,
                       const float* __restrict__ Wxc, const float* __restrict__ Wxo,
                       const float* __restrict__ Whi, const float* __restrict__ Whf,
                       const float* __restrict__ Whc, const float* __restrict__ Who,
                       ushort* __restrict__ Bp) {
  int idx = blockIdx.x * blockDim.x + threadIdx.x;
  if (idx >= 12 * 16 * 64 * 8) return;
  int j = idx & 7;
  int lane = (idx >> 3) & 63;
  int c = (idx >> 9) & 15;
  int t = idx >> 13;
  int k = t * 32 + (lane >> 4) * 8 + j;
  int col = c * 16 + (lane & 15);
  int g = col >> 6, oc = col & 63;
  int s = k >> 6, kk = k & 63, ord = s >> 1;
  const float* Wx[4] = {Wxi, Wxf, Wxc, Wxo};
  const float* Wh[4] = {Whi, Whf, Whc, Who};
  const float* W = (s & 1) ? Wh[g] : Wx[g];
  float v = W[(ord * 64 + kk) * 64 + oc];
  __hip_bfloat16 b = __float2bfloat16(v);
  Bp[idx] = *reinterpret_cast<ushort*>(&b);
}

__device__ __forceinline__ float frcp(float x) { return __builtin_amdgcn_rcpf(x); }

// MFMA GEMM + fused LSTM epilogue. A (quarter-major) prefetched to regs;
// B staged to LDS dbuf. Whole B-tile hoisted to regs BEFORE issuing next
// stage so no vmem-alias wait lands in front of the ds_reads.
__global__ __launch_bounds__(256) void k_mfma_lstm(
    const uint* __restrict__ XHq, const uint* __restrict__ T1q,
    const uint* __restrict__ T2q, const float* __restrict__ C,
    const ushort* __restrict__ Bp,
    const float* __restrict__ bxi, const float* __restrict__ bxf,
    const float* __restrict__ bxc, const float* __restrict__ bxo,
    const float* __restrict__ bhi, const float* __restrict__ bhf,
    const float* __restrict__ bhc, const float* __restrict__ bho,
    const float* __restrict__ wci, const float* __restrict__ wcf, const float* __restrict__ wco,
    const float* __restrict__ bi, const float* __restrict__ bf_,
    const float* __restrict__ bc_, const float* __restrict__ bo,
    float* __restrict__ Hout, float* __restrict__ Cout) {
  __shared__ ushort bsh[2][8192];  // 2 x 16 KB B tiles
  int lane = threadIdx.x & 63, wid = threadIdx.x >> 6;
  int row0 = blockIdx.x * 64 + wid * 16;
  int ar = row0 + (lane & 15);
  if (ar > N_NODES - 1) ar = N_NODES - 1;  // clamp: dup rows, outputs masked later

#define STAGE(buf, t)                                                          \
  {                                                                            \
    _Pragma("unroll") for (int qq = 0; qq < 4; ++qq) {                         \
      int seg = wid * 4 + qq;                                                  \
      __builtin_amdgcn_global_load_lds(                                        \
          (const __attribute__((address_space(1))) uint*)(Bp + (t)*8192 +     \
                                                          seg * 512 + lane * 8),\
          (__attribute__((address_space(3))) uint*)&bsh[buf][seg * 512],       \
          16, 0, 0);                                                           \
    }                                                                          \
  }

  STAGE(0, 0)

  const ushort* XHs = (const ushort*)XHq;
  const ushort* T1s = (const ushort*)T1q;
  const ushort* T2s = (const ushort*)T2q;
  s8v a[12];
#pragma unroll
  for (int q = 0; q < 4; ++q) {
    long off = ((long)q * N_NODES + ar) * 32 + (lane >> 4) * 8;
    a[q]     = *(const s8v*)(XHs + off);
    a[4 + q] = *(const s8v*)(T1s + off);
    a[8 + q] = *(const s8v*)(T2s + off);
  }

  f32x4 acc[16];
#pragma unroll
  for (int c = 0; c < 16; ++c) acc[c] = {0.f, 0.f, 0.f, 0.f};

#pragma unroll
  for (int t = 0; t < 12; ++t) {
    int buf = t & 1;
    __syncthreads();             // drains stage(t); nothing else outstanding
    s8v bfr[16];
#pragma unroll
    for (int c = 0; c < 16; ++c)
      bfr[c] = *(const s8v*)(&bsh[buf][c * 512 + lane * 8]);
    if (t < 11) STAGE(buf ^ 1, t + 1)   // DMA overlaps the 16 MFMAs below
#pragma unroll
    for (int c = 0; c < 16; ++c)
      acc[c] = __builtin_amdgcn_mfma_f32_16x16x32_bf16(a[t], bfr[c], acc[c], 0, 0, 0);
  }
#undef STAGE

  int rbase = row0 + ((lane >> 4) << 2);
  int ocl = lane & 15;
#pragma unroll
  for (int j = 0; j < 4; ++j) {
    int oc = j * 16 + ocl;
    float bI = bxi[oc] + bhi[oc] + bi[oc];
    float bF = bxf[oc] + bhf[oc] + bf_[oc];
    float bT = bxc[oc] + bhc[oc] + bc_[oc];
    float bO = bxo[oc] + bho[oc] + bo[oc];
    float wcI = wci[oc], wcF = wcf[oc], wcO = wco[oc];
#pragma unroll
    for (int r = 0; r < 4; ++r) {
      int row = rbase + r;
      if (row < N_NODES) {
        float cv = C[(long)row * 64 + oc];
        float I = frcp(1.f + __expf(-(acc[j][r] + bI + wcI * cv)));
        float F = frcp(1.f + __expf(-(acc[4 + j][r] + bF + wcF * cv)));
        float e2 = __expf(2.f * (acc[8 + j][r] + bT));
        float T = 1.f - 2.f * frcp(e2 + 1.f);
        float cn = F * cv + I * T;
        float O = frcp(1.f + __expf(-(acc[12 + j][r] + bO + wcO * cn)));
        float e2c = __expf(2.f * cn);
        float tc = 1.f - 2.f * frcp(e2c + 1.f);
        Hout[(long)row * 64 + oc] = O * tc;
        Cout[(long)row * 64 + oc] = cn;
      }
    }
  }
}

extern "C" void kernel_launch(void* const* d_in, const int* in_sizes, int n_in,
                              void* d_out, int out_size, void* d_ws, size_t ws_size,
                              hipStream_t stream) {
  (void)in_sizes; (void)n_in; (void)out_size; (void)ws_size;
  const float* X   = (const float*)d_in[0];
  const int*   ei  = (const int*)d_in[1];
  const float* ew  = (const float*)d_in[2];
  const float* H   = (const float*)d_in[3];
  const float* C   = (const float*)d_in[4];
  const float* Wxi = (const float*)d_in[5];
  const float* bxi = (const float*)d_in[6];
  const float* Wxf = (const float*)d_in[7];
  const float* bxf = (const float*)d_in[8];
  const float* Wxc = (const float*)d_in[9];
  const float* bxc = (const float*)d_in[10];
  const float* Wxo = (const float*)d_in[11];
  const float* bxo = (const float*)d_in[12];
  const float* Whi = (const float*)d_in[13];
  const float* bhi = (const float*)d_in[14];
  const float* Whf = (const float*)d_in[15];
  const float* bhf = (const float*)d_in[16];
  const float* Whc = (const float*)d_in[17];
  const float* bhc = (const float*)d_in[18];
  const float* Who = (const float*)d_in[19];
  const float* bho = (const float*)d_in[20];
  const float* wci = (const float*)d_in[21];
  const float* wcf = (const float*)d_in[22];
  const float* wco = (const float*)d_in[23];
  const float* bi  = (const float*)d_in[24];
  const float* bf_ = (const float*)d_in[25];
  const float* bc_ = (const float*)d_in[26];
  const float* bo  = (const float*)d_in[27];

  float* ws = (float*)d_ws;
  uint*   blkh  = (uint*)(ws + O_BLKH);
  uint*   bbase = (uint*)(ws + O_BBASE);
  uint*   bsum  = (uint*)(ws + O_BSUM);
  int*    cnt   = (int*)(ws + O_CNT);
  float*  dinv  = ws + O_DINV;
  int*    rptr  = (int*)(ws + O_RPTR);
  unsigned long long* srec  = (unsigned long long*)(ws + O_SREC);
  unsigned long long* srec2 = (unsigned long long*)(ws + O_SREC2);
  uint*   edges = (uint*)(ws + O_EDGE);
  uint*   XHq   = (uint*)(ws + O_XHQ);
  uint*   T1q   = (uint*)(ws + O_T1Q);
  uint*   T2q   = (uint*)(ws + O_T2Q);
  ushort* Bp    = (ushort*)(ws + O_BP);

  float* Hout = (float*)d_out;
  float* Cout = Hout + N_NODES * 64;

  k_hist<<<PBLK, 256, 0, stream>>>(ei, blkh);
  k_bsum_scan<<<NBKT, 256, 0, stream>>>(blkh, bsum);
  k_bscan<<<1, 256, 0, stream>>>(bsum, bbase);
  k_scatter_b<<<PBLK, 256, 0, stream>>>(ei, ew, blkh, bbase, srec);
  k_csr<<<NBKT, 256, 0, stream>>>(srec, bbase, srec2, cnt, dinv, rptr);
  k_finalize<<<NBKT, 256, 0, stream>>>(srec2, bbase, dinv, edges);
  k_xhb<<<(N_NODES * 64 + 255) / 256, 256, 0, stream>>>(X, H, XHq);
  k_pack<<<(12 * 16 * 64 * 8 + 255) / 256, 256, 0, stream>>>(Wxi, Wxf, Wxc, Wxo,
                                                             Whi, Whf, Whc, Who, Bp);
  // T1 = L @ XH ; T2 = 2 L @ T1 - XH   (quarter-major, 50000 blocks each)
  k_spmm2q<<<N_NODES, 256, 0, stream>>>(XHq, XHq, 1.f, 0.f, rptr, cnt, edges, T1q);
  k_spmm2q<<<N_NODES, 256, 0, stream>>>(T1q, XHq, 2.f, -1.f, rptr, cnt, edges, T2q);
  k_mfma_lstm<<<(N_NODES + 63) / 64, 256, 0, stream>>>(
      XHq, T1q, T2q, C, Bp,
      bxi, bxf, bxc, bxo, bhi, bhf, bhc, bho,
      wci, wcf, wco, bi, bf_, bc_, bo, Hout, Cout);
}

// Round 11
// 218.325 us; speedup vs baseline: 1.7700x; 1.4691x over previous
//
#include <hip/hip_runtime.h>
#include <hip/hip_bf16.h>
#include <math.h>

#define N_NODES 50000
#define E_EDGES 1600000
#define NBKT 196          // row buckets of 256 rows
#define PBLK 400          // blocks in hist/scatter phases
#define CHUNK 4000        // edges per block (PBLK*CHUNK == E_EDGES)

typedef __attribute__((ext_vector_type(8))) short s8v;    // 8 bf16 frag
typedef __attribute__((ext_vector_type(4))) float f32x4;  // mfma acc

// ---------------- workspace layout (float units) ----------------
#define O_BLKH  0          // 196*400 u32, local-scanned in place
#define O_BBASE 78592      // 197 u32 bucket bases
#define O_BSUM  78848      // 196 u32 bucket totals
#define O_CNT   79104      // 50000 i32
#define O_DINV  129152     // 50000 f32
#define O_RPTR  179200     // 50000 i32
#define O_SREC  229248     // 1.6M u64 records = 3.2M floats
#define O_SREC2 3429248    // 1.6M u64 sorted records
#define O_EDGE  O_SREC     // alias: final u32 edges (srec dead after k_csr)
#define O_XHB   O_SREC2    // alias: row-major [N][64 u32] (srec2 dead)
#define O_T1B   6629248
#define O_T2B   9829248
#define O_BP    13029248   // 98304 bf16
// end: 13078400 floats ~= 52.3 MB

__device__ __forceinline__ uint pk_bf16(float x, float y) {
  __hip_bfloat16 bx = __float2bfloat16(x), by = __float2bfloat16(y);
  ushort ux = *reinterpret_cast<ushort*>(&bx);
  ushort uy = *reinterpret_cast<ushort*>(&by);
  return ((uint)uy << 16) | (uint)ux;
}

// ---- phase 1: per-block bucket histogram (no global atomics) ----
__global__ __launch_bounds__(256) void k_hist(const int* __restrict__ ei,
                                              uint* __restrict__ blkh) {
  __shared__ uint h[NBKT];
  int blk = blockIdx.x, tid = threadIdx.x;
  for (int i = tid; i < NBKT; i += 256) h[i] = 0;
  __syncthreads();
  int e0 = blk * CHUNK;
  for (int i = tid; i < CHUNK; i += 256) {
    int e = e0 + i;
    int r = ei[e], c = ei[E_EDGES + e];
    if (r != c) atomicAdd(&h[r >> 8], 1u);
  }
  __syncthreads();
  for (int i = tid; i < NBKT; i += 256) blkh[i * PBLK + blk] = h[i];  // [bucket][block]
}

// ---- phase 2a: per-bucket exclusive scan of its 400 block counts + total ----
__global__ __launch_bounds__(256) void k_bsum_scan(uint* __restrict__ blkh,
                                                   uint* __restrict__ bsum) {
  __shared__ uint sh[512];
  int b = blockIdx.x, t = threadIdx.x;
  uint v0 = (t < PBLK) ? blkh[b * PBLK + t] : 0u;
  uint v1 = (t + 256 < PBLK) ? blkh[b * PBLK + t + 256] : 0u;
  sh[t] = v0; sh[t + 256] = v1;
  __syncthreads();
  for (int off = 1; off < 512; off <<= 1) {
    uint x0 = sh[t], x1 = sh[t + 256];
    uint a0 = (t >= off) ? sh[t - off] : 0u;
    uint a1 = (t + 256 >= off) ? sh[t + 256 - off] : 0u;
    __syncthreads();
    sh[t] = x0 + a0; sh[t + 256] = x1 + a1;
    __syncthreads();
  }
  if (t < PBLK) blkh[b * PBLK + t] = sh[t] - v0;          // local exclusive
  if (t + 256 < PBLK) blkh[b * PBLK + t + 256] = sh[t + 256] - v1;
  if (t == 0) bsum[b] = sh[511];
}

// ---- phase 2b: scan 196 bucket totals -> bbase[0..196] ----
__global__ __launch_bounds__(256) void k_bscan(const uint* __restrict__ bsum,
                                               uint* __restrict__ bbase) {
  __shared__ uint sh[256];
  int t = threadIdx.x;
  uint v = (t < NBKT) ? bsum[t] : 0u;
  sh[t] = v;
  __syncthreads();
  for (int off = 1; off < 256; off <<= 1) {
    uint a = (t >= off) ? sh[t - off] : 0u;
    __syncthreads();
    sh[t] += a;
    __syncthreads();
  }
  if (t < NBKT) bbase[t] = sh[t] - v;
  if (t == 255) bbase[NBKT] = sh[255];
}

// ---- phase 3: scatter edges to bucket-contiguous u64 records via LDS cursors ----
__global__ __launch_bounds__(256) void k_scatter_b(const int* __restrict__ ei,
                                                   const float* __restrict__ ew,
                                                   const uint* __restrict__ off,
                                                   const uint* __restrict__ bbase,
                                                   unsigned long long* __restrict__ srec) {
  __shared__ uint cur[NBKT];
  int blk = blockIdx.x, tid = threadIdx.x;
  for (int i = tid; i < NBKT; i += 256) cur[i] = off[i * PBLK + blk] + bbase[i];
  __syncthreads();
  int e0 = blk * CHUNK;
  for (int i = tid; i < CHUNK; i += 256) {
    int e = e0 + i;
    int r = ei[e], c = ei[E_EDGES + e];
    if (r != c) {
      uint pos = atomicAdd(&cur[r >> 8], 1u);
      srec[pos] = ((unsigned long long)(r & 255) << 48) |
                  ((unsigned long long)(uint)c << 32) |
                  (unsigned long long)__float_as_uint(ew[e]);
    }
  }
}

// ---- phase 4: per-bucket CSR build + degree/dinv (LDS atomics only) ----
__global__ __launch_bounds__(256) void k_csr(const unsigned long long* __restrict__ srec,
                                             const uint* __restrict__ bbase,
                                             unsigned long long* __restrict__ srec2,
                                             int* __restrict__ cnt, float* __restrict__ dinv,
                                             int* __restrict__ rptr) {
  __shared__ uint hc[256], hs[256], cur[256], wsum[4];
  int b = blockIdx.x, t = threadIdx.x;
  uint start = bbase[b], endv = bbase[b + 1];
  hc[t] = 0; hs[t] = 0;
  __syncthreads();
  for (uint i = start + t; i < endv; i += 256) {
    unsigned long long rec = srec[i];
    int rl = (int)(rec >> 48);
    float w = __uint_as_float((uint)rec);
    atomicAdd(&hc[rl], 1u);
    atomicAdd(&hs[rl], (uint)(w * 1048576.0f + 0.5f));  // fixed 2^20
  }
  __syncthreads();
  int lane = t & 63, wid = t >> 6;
  uint myc = hc[t];
  uint x = myc;
#pragma unroll
  for (int off = 1; off < 64; off <<= 1) {
    uint y = __shfl_up(x, off);
    if (lane >= off) x += y;
  }
  if (lane == 63) wsum[wid] = x;
  __syncthreads();
  uint woff = 0;
#pragma unroll
  for (int j = 0; j < 4; ++j) if (j < wid) woff += wsum[j];
  uint excl = woff + x - myc;
  int row = b * 256 + t;
  if (row < N_NODES) {
    float d = (float)hs[t] * (1.0f / 1048576.0f);
    dinv[row] = d > 0.f ? rsqrtf(d) : 0.f;
    cnt[row] = (int)myc;
    rptr[row] = (int)(start + excl);
  }
  cur[t] = start + excl;
  __syncthreads();
  for (uint i = start + t; i < endv; i += 256) {
    unsigned long long rec = srec[i];
    int rl = (int)(rec >> 48);
    uint pos = atomicAdd(&cur[rl], 1u);
    srec2[pos] = rec;
  }
}

// ---- phase 5: fold dinv into weights, emit final u32 edge records ----
__global__ __launch_bounds__(256) void k_finalize(const unsigned long long* __restrict__ srec2,
                                                  const uint* __restrict__ bbase,
                                                  const float* __restrict__ dinv,
                                                  uint* __restrict__ edges) {
  int b = blockIdx.x, t = threadIdx.x;
  uint start = bbase[b], endv = bbase[b + 1];
  for (uint i = start + t; i < endv; i += 256) {
    unsigned long long rec = srec2[i];
    int rl = (int)(rec >> 48);
    int c = (int)((rec >> 32) & 0xffff);
    float w = __uint_as_float((uint)rec);
    int r = b * 256 + rl;
    float wn = -w * dinv[r] * dinv[c];
    __hip_bfloat16 bw = __float2bfloat16(wn);
    edges[i] = ((uint)c << 16) | (uint)*reinterpret_cast<ushort*>(&bw);
  }
}

// XHb[n] = bf16x2-packed [X[n] | H[n]], row-major [N][64 u32]
__global__ void k_xhb(const float* __restrict__ X, const float* __restrict__ Hm,
                      uint* __restrict__ XHb) {
  int t = blockIdx.x * blockDim.x + threadIdx.x;
  if (t >= N_NODES * 64) return;
  int n = t >> 6, q = t & 63;
  float2 v = (q < 32) ? *(const float2*)(X + (long)n * 64 + q * 2)
                      : *(const float2*)(Hm + (long)n * 64 + (q - 32) * 2);
  XHb[t] = pk_bf16(v.x, v.y);
}

// Dual-edge SpMM: wave per row; lane half (lane>>5) owns one edge of each pair,
// 32 lanes x uint2 (4 bf16 ch) cover the 128-ch row. shfl_xor(32) combines.
__global__ __launch_bounds__(256) void k_spmm2b(
    const uint* __restrict__ src, const uint* __restrict__ other,
    float alpha, float beta,
    const int* __restrict__ rptr, const int* __restrict__ cnt,
    const uint* __restrict__ edges, uint* __restrict__ out) {
  int wid = threadIdx.x >> 6, lane = threadIdx.x & 63;
  int row = blockIdx.x * 4 + wid;
  if (row >= N_NODES) return;
  int start = rptr[row], n = cnt[row];
  int half = lane >> 5;
  int l5 = lane & 31;
  float ax = 0.f, ay = 0.f, bx = 0.f, by = 0.f;
  for (int base = 0; base < n; base += 64) {
    int m = n - base; if (m > 64) m = 64;
    // coalesced 256B record load, zero-padded (rec=0 -> w=+0, cc=0: harmless)
    uint rec = (lane < m) ? edges[start + base + lane] : 0u;
    int iters = (m + 1) >> 1;
    int j = 0;
    for (; j + 4 <= iters; j += 4) {
#pragma unroll
      for (int u = 0; u < 4; ++u) {
        uint r = __shfl(rec, 2 * (j + u) + half);
        int cc = (int)(r >> 16);
        float ww = __uint_as_float(r << 16);
        uint2 z = *(const uint2*)(src + cc * 64 + (l5 << 1));
        ax = fmaf(ww, __uint_as_float(z.x << 16), ax);
        ay = fmaf(ww, __uint_as_float(z.x & 0xffff0000u), ay);
        bx = fmaf(ww, __uint_as_float(z.y << 16), bx);
        by = fmaf(ww, __uint_as_float(z.y & 0xffff0000u), by);
      }
    }
    for (; j < iters; ++j) {
      uint r = __shfl(rec, 2 * j + half);
      int cc = (int)(r >> 16);
      float ww = __uint_as_float(r << 16);
      uint2 z = *(const uint2*)(src + cc * 64 + (l5 << 1));
      ax = fmaf(ww, __uint_as_float(z.x << 16), ax);
      ay = fmaf(ww, __uint_as_float(z.x & 0xffff0000u), ay);
      bx = fmaf(ww, __uint_as_float(z.y << 16), bx);
      by = fmaf(ww, __uint_as_float(z.y & 0xffff0000u), by);
    }
  }
  ax += __shfl_xor(ax, 32); ay += __shfl_xor(ay, 32);
  bx += __shfl_xor(bx, 32); by += __shfl_xor(by, 32);
  if (half == 0) {
    long o = (long)row * 64 + (l5 << 1);
    float ox = alpha * ax, oy = alpha * ay;
    float px = alpha * bx, py = alpha * by;
    if (beta != 0.f) {
      uint2 ov = *(const uint2*)(other + o);
      ox += beta * __uint_as_float(ov.x << 16);
      oy += beta * __uint_as_float(ov.x & 0xffff0000u);
      px += beta * __uint_as_float(ov.y << 16);
      py += beta * __uint_as_float(ov.y & 0xffff0000u);
    }
    uint2 w2; w2.x = pk_bf16(ox, oy); w2.y = pk_bf16(px, py);
    *(uint2*)(out + o) = w2;
  }
}

// B-frag pack: Bp[((t*16+c)*64+lane)*8+j] = bf16(W[k][col]), k=t*32+(lane>>4)*8+j,
// col = c*16+(lane&15); col = g*64+oc; k-slice s=k/64: even->Wx[g], odd->Wh[g], ord=s>>1
__global__ void k_pack(const float* __restrict__ Wxi, const float* __restrict__ Wxf,
                       const float* __restrict__ Wxc, const float* __restrict__ Wxo,
                       const float* __restrict__ Whi, const float* __restrict__ Whf,
                       const float* __restrict__ Whc, const float* __restrict__ Who,
                       ushort* __restrict__ Bp) {
  int idx = blockIdx.x * blockDim.x + threadIdx.x;
  if (idx >= 12 * 16 * 64 * 8) return;
  int j = idx & 7;
  int lane = (idx >> 3) & 63;
  int c = (idx >> 9) & 15;
  int t = idx >> 13;
  int k = t * 32 + (lane >> 4) * 8 + j;
  int col = c * 16 + (lane & 15);
  int g = col >> 6, oc = col & 63;
  int s = k >> 6, kk = k & 63, ord = s >> 1;
  const float* Wx[4] = {Wxi, Wxf, Wxc, Wxo};
  const float* Wh[4] = {Whi, Whf, Whc, Who};
  const float* W = (s & 1) ? Wh[g] : Wx[g];
  float v = W[(ord * 64 + kk) * 64 + oc];
  __hip_bfloat16 b = __float2bfloat16(v);
  Bp[idx] = *reinterpret_cast<ushort*>(&b);
}

__device__ __forceinline__ float frcp(float x) { return __builtin_amdgcn_rcpf(x); }

// MFMA GEMM + fused LSTM epilogue. 32 rows/block (2 waves) for 2x grid
// parallelism; A row-major prefetched; B LDS dbuf with full reg-hoist
// before next STAGE issue (no vmem-alias wait in front of ds_reads).
__global__ __launch_bounds__(128) void k_mfma_lstm(
    const uint* __restrict__ XHb, const uint* __restrict__ T1b,
    const uint* __restrict__ T2b, const float* __restrict__ C,
    const ushort* __restrict__ Bp,
    const float* __restrict__ bxi, const float* __restrict__ bxf,
    const float* __restrict__ bxc, const float* __restrict__ bxo,
    const float* __restrict__ bhi, const float* __restrict__ bhf,
    const float* __restrict__ bhc, const float* __restrict__ bho,
    const float* __restrict__ wci, const float* __restrict__ wcf, const float* __restrict__ wco,
    const float* __restrict__ bi, const float* __restrict__ bf_,
    const float* __restrict__ bc_, const float* __restrict__ bo,
    float* __restrict__ Hout, float* __restrict__ Cout) {
  __shared__ ushort bsh[2][8192];  // 2 x 16 KB B tiles
  int lane = threadIdx.x & 63, wid = threadIdx.x >> 6;  // wid 0..1
  int row0 = blockIdx.x * 32 + wid * 16;
  int ar = row0 + (lane & 15);
  if (ar > N_NODES - 1) ar = N_NODES - 1;  // clamp: dup rows, outputs masked later

#define STAGE(buf, t)                                                          \
  {                                                                            \
    _Pragma("unroll") for (int qq = 0; qq < 8; ++qq) {                         \
      int seg = wid * 8 + qq;                                                  \
      __builtin_amdgcn_global_load_lds(                                        \
          (const __attribute__((address_space(1))) uint*)(Bp + (t)*8192 +     \
                                                          seg * 512 + lane * 8),\
          (__attribute__((address_space(3))) uint*)&bsh[buf][seg * 512],       \
          16, 0, 0);                                                           \
    }                                                                          \
  }

  STAGE(0, 0)

  const ushort* XHs = (const ushort*)XHb;
  const ushort* T1s = (const ushort*)T1b;
  const ushort* T2s = (const ushort*)T2b;
  long abase = (long)ar * 128 + (lane >> 4) * 8;
  s8v a[12];
#pragma unroll
  for (int q = 0; q < 4; ++q) a[q] = *(const s8v*)(XHs + abase + q * 32);
#pragma unroll
  for (int q = 0; q < 4; ++q) a[4 + q] = *(const s8v*)(T1s + abase + q * 32);
#pragma unroll
  for (int q = 0; q < 4; ++q) a[8 + q] = *(const s8v*)(T2s + abase + q * 32);

  f32x4 acc[16];
#pragma unroll
  for (int c = 0; c < 16; ++c) acc[c] = {0.f, 0.f, 0.f, 0.f};

#pragma unroll
  for (int t = 0; t < 12; ++t) {
    int buf = t & 1;
    __syncthreads();             // drains stage(t); prev ds_reads done
    s8v bfr[16];
#pragma unroll
    for (int c = 0; c < 16; ++c)
      bfr[c] = *(const s8v*)(&bsh[buf][c * 512 + lane * 8]);
    if (t < 11) STAGE(buf ^ 1, t + 1)   // DMA overlaps the 16 MFMAs below
#pragma unroll
    for (int c = 0; c < 16; ++c)
      acc[c] = __builtin_amdgcn_mfma_f32_16x16x32_bf16(a[t], bfr[c], acc[c], 0, 0, 0);
  }
#undef STAGE

  int rbase = row0 + ((lane >> 4) << 2);
  int ocl = lane & 15;
#pragma unroll
  for (int j = 0; j < 4; ++j) {
    int oc = j * 16 + ocl;
    float bI = bxi[oc] + bhi[oc] + bi[oc];
    float bF = bxf[oc] + bhf[oc] + bf_[oc];
    float bT = bxc[oc] + bhc[oc] + bc_[oc];
    float bO = bxo[oc] + bho[oc] + bo[oc];
    float wcI = wci[oc], wcF = wcf[oc], wcO = wco[oc];
#pragma unroll
    for (int r = 0; r < 4; ++r) {
      int row = rbase + r;
      if (row < N_NODES) {
        float cv = C[(long)row * 64 + oc];
        float I = frcp(1.f + __expf(-(acc[j][r] + bI + wcI * cv)));
        float F = frcp(1.f + __expf(-(acc[4 + j][r] + bF + wcF * cv)));
        float e2 = __expf(2.f * (acc[8 + j][r] + bT));
        float T = 1.f - 2.f * frcp(e2 + 1.f);
        float cn = F * cv + I * T;
        float O = frcp(1.f + __expf(-(acc[12 + j][r] + bO + wcO * cn)));
        float e2c = __expf(2.f * cn);
        float tc = 1.f - 2.f * frcp(e2c + 1.f);
        Hout[(long)row * 64 + oc] = O * tc;
        Cout[(long)row * 64 + oc] = cn;
      }
    }
  }
}

extern "C" void kernel_launch(void* const* d_in, const int* in_sizes, int n_in,
                              void* d_out, int out_size, void* d_ws, size_t ws_size,
                              hipStream_t stream) {
  (void)in_sizes; (void)n_in; (void)out_size; (void)ws_size;
  const float* X   = (const float*)d_in[0];
  const int*   ei  = (const int*)d_in[1];
  const float* ew  = (const float*)d_in[2];
  const float* H   = (const float*)d_in[3];
  const float* C   = (const float*)d_in[4];
  const float* Wxi = (const float*)d_in[5];
  const float* bxi = (const float*)d_in[6];
  const float* Wxf = (const float*)d_in[7];
  const float* bxf = (const float*)d_in[8];
  const float* Wxc = (const float*)d_in[9];
  const float* bxc = (const float*)d_in[10];
  const float* Wxo = (const float*)d_in[11];
  const float* bxo = (const float*)d_in[12];
  const float* Whi = (const float*)d_in[13];
  const float* bhi = (const float*)d_in[14];
  const float* Whf = (const float*)d_in[15];
  const float* bhf = (const float*)d_in[16];
  const float* Whc = (const float*)d_in[17];
  const float* bhc = (const float*)d_in[18];
  const float* Who = (const float*)d_in[19];
  const float* bho = (const float*)d_in[20];
  const float* wci = (const float*)d_in[21];
  const float* wcf = (const float*)d_in[22];
  const float* wco = (const float*)d_in[23];
  const float* bi  = (const float*)d_in[24];
  const float* bf_ = (const float*)d_in[25];
  const float* bc_ = (const float*)d_in[26];
  const float* bo  = (const float*)d_in[27];

  float* ws = (float*)d_ws;
  uint*   blkh  = (uint*)(ws + O_BLKH);
  uint*   bbase = (uint*)(ws + O_BBASE);
  uint*   bsum  = (uint*)(ws + O_BSUM);
  int*    cnt   = (int*)(ws + O_CNT);
  float*  dinv  = ws + O_DINV;
  int*    rptr  = (int*)(ws + O_RPTR);
  unsigned long long* srec  = (unsigned long long*)(ws + O_SREC);
  unsigned long long* srec2 = (unsigned long long*)(ws + O_SREC2);
  uint*   edges = (uint*)(ws + O_EDGE);
  uint*   XHb   = (uint*)(ws + O_XHB);
  uint*   T1b   = (uint*)(ws + O_T1B);
  uint*   T2b   = (uint*)(ws + O_T2B);
  ushort* Bp    = (ushort*)(ws + O_BP);

  float* Hout = (float*)d_out;
  float* Cout = Hout + N_NODES * 64;

  k_hist<<<PBLK, 256, 0, stream>>>(ei, blkh);
  k_bsum_scan<<<NBKT, 256, 0, stream>>>(blkh, bsum);
  k_bscan<<<1, 256, 0, stream>>>(bsum, bbase);
  k_scatter_b<<<PBLK, 256, 0, stream>>>(ei, ew, blkh, bbase, srec);
  k_csr<<<NBKT, 256, 0, stream>>>(srec, bbase, srec2, cnt, dinv, rptr);
  k_finalize<<<NBKT, 256, 0, stream>>>(srec2, bbase, dinv, edges);
  k_xhb<<<(N_NODES * 64 + 255) / 256, 256, 0, stream>>>(X, H, XHb);
  k_pack<<<(12 * 16 * 64 * 8 + 255) / 256, 256, 0, stream>>>(Wxi, Wxf, Wxc, Wxo,
                                                             Whi, Whf, Whc, Who, Bp);
  int spmm_grid = (N_NODES + 3) / 4;
  // T1 = L @ XH
  k_spmm2b<<<spmm_grid, 256, 0, stream>>>(XHb, XHb, 1.f, 0.f, rptr, cnt, edges, T1b);
  // T2 = 2 L @ T1 - XH
  k_spmm2b<<<spmm_grid, 256, 0, stream>>>(T1b, XHb, 2.f, -1.f, rptr, cnt, edges, T2b);
  k_mfma_lstm<<<(N_NODES + 31) / 32, 128, 0, stream>>>(
      XHb, T1b, T2b, C, Bp,
      bxi, bxf, bxc, bxo, bhi, bhf, bhc, bho,
      wci, wcf, wco, bi, bf_, bc_, bo, Hout, Cout);
}